// Round 1
// baseline (101.331 us; speedup 1.0000x reference)
//
#include <hip/hip_runtime.h>

#define H     300
#define MID   100
#define NN    1024
#define NP1   1025
#define JST   1088   // padded j-extent of E4 (E4[25][1088][4] floats)

typedef float v2f __attribute__((ext_vector_type(2)));
static __device__ __forceinline__ v2f sp2(float s) { return (v2f){s, s}; }
static __device__ __forceinline__ v2f fma2(v2f a, v2f b, v2f c) {
    return __builtin_elementwise_fma(a, b, c);
}

// ---------------------------------------------------------------------------
// Kernel A: precompute s1b and E4 straight from row-major W1.
// 512 blocks x 256 threads; block b -> items iA=2b, iB=2b+1.
// Each wave splits into two 32-lane groups; each group owns one m and strides
// lanes over h (128B-contiguous coalesced W1 reads). Sentence rows in LDS.
// 5-step __shfl_xor butterfly per dot. Waves 0,1 -> s1b rows (s1 = dot+b1).
// Waves 2,3 -> E4[m>>2][j][m&3] = exp2(s2 * -log2e)   (j = item+1).
// ---------------------------------------------------------------------------
__global__ __launch_bounds__(256) void precompute_kernel(
    const float* __restrict__ sentence,
    const float* __restrict__ W1,
    const float* __restrict__ b1,
    float* __restrict__ s1b,
    float* __restrict__ E4,
    float* __restrict__ out)
{
    __shared__ float rA[H];
    __shared__ float rB[H];
    const int tid = threadIdx.x;
    const int iA = blockIdx.x * 2, iB = iA + 1;
    const float NL = -1.4426950408889634f;

    if (blockIdx.x == 0) {
        if (tid == 0) out[0] = 0.0f;                              // loss accumulator
        if (tid < MID)
            E4[(long)((tid >> 2) * JST) * 4 + (tid & 3)] = 1.0f;  // j=0 column
    }

    const float* sA = sentence + (long)iA * H;
    const float* sB = sentence + (long)iB * H;
    for (int idx = tid; idx < 2 * H; idx += 256) {
        if (idx < H) rA[idx] = sA[idx];
        else         rB[idx - H] = sB[idx - H];
    }
    __syncthreads();

    const int wv   = tid >> 6;
    const int lane = tid & 63;
    const int sub  = lane >> 5;
    const int hb   = lane & 31;
    const int half = wv >> 1;
    const int mb   = (wv & 1) * 50;

    for (int q = 0; q < 25; ++q) {
        const int m = mb + 2 * q + sub;
        const float* wrow = W1 + (long)m * (2 * H) + half * H;
        float aA = 0.f, aB = 0.f;
        #pragma unroll
        for (int k = 0; k < 9; ++k) {
            const int h = hb + 32 * k;
            const float w = wrow[h];
            aA = __builtin_fmaf(w, rA[h], aA);
            aB = __builtin_fmaf(w, rB[h], aB);
        }
        if (hb < 12) {
            const int h = hb + 288;
            const float w = wrow[h];
            aA = __builtin_fmaf(w, rA[h], aA);
            aB = __builtin_fmaf(w, rB[h], aB);
        }
        #pragma unroll
        for (int off = 16; off > 0; off >>= 1) {
            aA += __shfl_xor(aA, off, 64);
            aB += __shfl_xor(aB, off, 64);
        }
        if (hb == 0) {
            if (half == 0) {
                const float bb = b1[m];
                s1b[iA * MID + m] = aA + bb;
                s1b[iB * MID + m] = aB + bb;
            } else {
                float* base = E4 + (long)((m >> 2) * JST) * 4 + (m & 3);
                base[(long)(iA + 1) * 4] = __builtin_amdgcn_exp2f(aA * NL);
                base[(long)(iB + 1) * 4] = __builtin_amdgcn_exp2f(aB * NL);
            }
        }
    }
}

// ---------------------------------------------------------------------------
// Kernel B: 256 blocks x 512 threads. Block handles 4 rows i0..i0+3; each
// thread handles TWO columns jA = tid, jB = tid + 512 (both coalesced).
// Rationale: the per-quad LDS broadcasts (4x Fq float4 + 1x W2 quad = 80 B)
// are column-independent; amortizing them over 2 columns halves LDS
// wave-instructions per term AND doubles per-wave ILP (two independent
// FMA/rcp chains), attacking the lgkmcnt-stall regime the 101.6us version
// appears to sit in (measured time ~7x above the single-pipe roofline).
// sigmoid(s1+x) = 1/(1 + E*F): E pre-stored (E4, float4 per m-quad), F per
// row in LDS. Quad-rcp per row-pair; rows packed as float2 ext-vectors so
// the symmetric VALU work lowers to v_pk_*_f32:
//   w0/A+w1/B+w2/C+w3/D = [fma(w0,B,w1*A)*CD + fma(w2,D,w3*C)*AB] * rcp(ABCD)
// ---------------------------------------------------------------------------
__global__ __launch_bounds__(512, 2) void main_kernel(
    const float* __restrict__ s1b,
    const float* __restrict__ E4,
    const float* __restrict__ W2,
    const float* __restrict__ b2,
    const int*   __restrict__ target,
    float* __restrict__ out)
{
    __shared__ float4 Fq[MID];          // {F_row0..F_row3}[m]
    __shared__ float4 w4sh[MID / 4];    // W2 m-quads
    __shared__ float  tmp[4][104];      // remainder-column partials per row
    __shared__ float  redl[8];
    __shared__ float4 redm[8];
    __shared__ float4 rede[8];
    __shared__ float  sc4sh[4];
    __shared__ float4 bmax, binv;

    const int i0  = blockIdx.x * 4;
    const int tid = threadIdx.x;
    const int lane = tid & 63, wv = tid >> 6;
    const float NL  = -1.4426950408889634f;
    const float L2E =  1.4426950408889634f;
    const v2f one2 = sp2(1.0f);

    if (tid < MID) {
        Fq[tid] = make_float4(
            __builtin_amdgcn_exp2f(s1b[(i0 + 0) * MID + tid] * NL),
            __builtin_amdgcn_exp2f(s1b[(i0 + 1) * MID + tid] * NL),
            __builtin_amdgcn_exp2f(s1b[(i0 + 2) * MID + tid] * NL),
            __builtin_amdgcn_exp2f(s1b[(i0 + 3) * MID + tid] * NL));
    } else if (tid >= 128 && tid < 128 + MID / 4) {
        const int p = tid - 128;
        w4sh[p] = make_float4(W2[4 * p], W2[4 * p + 1], W2[4 * p + 2], W2[4 * p + 3]);
    }
    const float b2v = b2[0];
    __syncthreads();

    // coalesced: column j reads float4 at E4 + (p*JST + j)*4
    #define LDXA(p_) (*(const float4*)(E4 + ((long)(p_) * JST + tid) * 4))
    #define LDXB(p_) (*(const float4*)(E4 + ((long)(p_) * JST + tid + 512) * 4))

    v2f acc01a = sp2(0.f), acc23a = sp2(0.f);
    v2f acc01b = sp2(0.f), acc23b = sp2(0.f);

    #define QCOL(X, accLo, accHi)                                             \
        do {                                                                  \
            const v2f e0 = sp2((X).x), e1 = sp2((X).y);                       \
            const v2f e2 = sp2((X).z), e3 = sp2((X).w);                       \
            {   /* rows 0,1 */                                                \
                const v2f A = fma2(e0, (v2f){F0.x, F0.y}, one2);              \
                const v2f B = fma2(e1, (v2f){F1.x, F1.y}, one2);              \
                const v2f C = fma2(e2, (v2f){F2.x, F2.y}, one2);              \
                const v2f D = fma2(e3, (v2f){F3.x, F3.y}, one2);              \
                const v2f AB = A * B, CD = C * D, P = AB * CD;                \
                const v2f R = {__builtin_amdgcn_rcpf(P.x),                    \
                               __builtin_amdgcn_rcpf(P.y)};                   \
                const v2f n1 = fma2(w0, B, w1 * A);                           \
                const v2f n2 = fma2(w2v, D, w3 * C);                          \
                accLo = fma2(fma2(n1, CD, n2 * AB), R, accLo);                \
            }                                                                 \
            {   /* rows 2,3 */                                                \
                const v2f A = fma2(e0, (v2f){F0.z, F0.w}, one2);              \
                const v2f B = fma2(e1, (v2f){F1.z, F1.w}, one2);              \
                const v2f C = fma2(e2, (v2f){F2.z, F2.w}, one2);              \
                const v2f D = fma2(e3, (v2f){F3.z, F3.w}, one2);              \
                const v2f AB = A * B, CD = C * D, P = AB * CD;                \
                const v2f R = {__builtin_amdgcn_rcpf(P.x),                    \
                               __builtin_amdgcn_rcpf(P.y)};                   \
                const v2f n1 = fma2(w0, B, w1 * A);                           \
                const v2f n2 = fma2(w2v, D, w3 * C);                          \
                accHi = fma2(fma2(n1, CD, n2 * AB), R, accHi);                \
            }                                                                 \
        } while (0)

    #define QBODY(p_, XA, XB)                                                 \
        do {                                                                  \
            const float4 F0 = Fq[4 * (p_)];                                   \
            const float4 F1 = Fq[4 * (p_) + 1];                               \
            const float4 F2 = Fq[4 * (p_) + 2];                               \
            const float4 F3 = Fq[4 * (p_) + 3];                               \
            const float4 w  = w4sh[p_];                                       \
            const v2f w0 = sp2(w.x), w1 = sp2(w.y);                           \
            const v2f w2v = sp2(w.z), w3 = sp2(w.w);                          \
            QCOL(XA, acc01a, acc23a);                                         \
            QCOL(XB, acc01b, acc23b);                                         \
        } while (0)

    // 25 m-quads, distance-2 software pipeline on the float4 loads
    float4 xa0 = LDXA(0), xb0 = LDXB(0);
    float4 xa1 = LDXA(1), xb1 = LDXB(1);
    #pragma unroll 2
    for (int p = 0; p < 23; ++p) {
        const float4 xan = LDXA(p + 2), xbn = LDXB(p + 2);
        QBODY(p, xa0, xb0);
        xa0 = xa1; xa1 = xan;
        xb0 = xb1; xb1 = xbn;
    }
    QBODY(23, xa0, xb0);
    QBODY(24, xa1, xb1);

    const float sc0a = acc01a.x + b2v, sc1a = acc01a.y + b2v;
    const float sc2a = acc23a.x + b2v, sc3a = acc23a.y + b2v;
    const float sc0b = acc01b.x + b2v, sc1b = acc01b.y + b2v;
    const float sc2b = acc23b.x + b2v, sc3b = acc23b.y + b2v;

    // ---- remainder column j = 1024 (4 rows) ----
    if (tid < MID) {
        const float E = E4[((long)(tid >> 2) * JST + 1024) * 4 + (tid & 3)];
        const float4 F = Fq[tid];
        const float wm = W2[tid];
        tmp[0][tid] = wm * __builtin_amdgcn_rcpf(__builtin_fmaf(E, F.x, 1.f));
        tmp[1][tid] = wm * __builtin_amdgcn_rcpf(__builtin_fmaf(E, F.y, 1.f));
        tmp[2][tid] = wm * __builtin_amdgcn_rcpf(__builtin_fmaf(E, F.z, 1.f));
        tmp[3][tid] = wm * __builtin_amdgcn_rcpf(__builtin_fmaf(E, F.w, 1.f));
    }
    __syncthreads();
    if (wv < 4) {
        float v = tmp[wv][lane] + ((lane < MID - 64) ? tmp[wv][lane + 64] : 0.f);
        #pragma unroll
        for (int off = 32; off > 0; off >>= 1) v += __shfl_down(v, off);
        if (lane == 0) sc4sh[wv] = v + b2v;
    }
    __syncthreads();

    // ---- loss + row-max (both columns folded per thread) ----
    const int tg0 = target[i0], tg1 = target[i0 + 1];
    const int tg2 = target[i0 + 2], tg3 = target[i0 + 3];
    const int jb = tid + 512;
    float ls = fabsf(sc0a - ((tid == tg0) ? 1.f : 0.f))
             + fabsf(sc1a - ((tid == tg1) ? 1.f : 0.f))
             + fabsf(sc2a - ((tid == tg2) ? 1.f : 0.f))
             + fabsf(sc3a - ((tid == tg3) ? 1.f : 0.f))
             + fabsf(sc0b - ((jb == tg0) ? 1.f : 0.f))
             + fabsf(sc1b - ((jb == tg1) ? 1.f : 0.f))
             + fabsf(sc2b - ((jb == tg2) ? 1.f : 0.f))
             + fabsf(sc3b - ((jb == tg3) ? 1.f : 0.f));
    float4 mx = make_float4(fmaxf(sc0a, sc0b), fmaxf(sc1a, sc1b),
                            fmaxf(sc2a, sc2b), fmaxf(sc3a, sc3b));
    if (tid == 0) {
        ls += fabsf(sc4sh[0] - ((1024 == tg0) ? 1.f : 0.f))
            + fabsf(sc4sh[1] - ((1024 == tg1) ? 1.f : 0.f))
            + fabsf(sc4sh[2] - ((1024 == tg2) ? 1.f : 0.f))
            + fabsf(sc4sh[3] - ((1024 == tg3) ? 1.f : 0.f));
        mx.x = fmaxf(mx.x, sc4sh[0]);
        mx.y = fmaxf(mx.y, sc4sh[1]);
        mx.z = fmaxf(mx.z, sc4sh[2]);
        mx.w = fmaxf(mx.w, sc4sh[3]);
    }
    #pragma unroll
    for (int off = 32; off > 0; off >>= 1) {
        ls += __shfl_down(ls, off);
        mx.x = fmaxf(mx.x, __shfl_down(mx.x, off));
        mx.y = fmaxf(mx.y, __shfl_down(mx.y, off));
        mx.z = fmaxf(mx.z, __shfl_down(mx.z, off));
        mx.w = fmaxf(mx.w, __shfl_down(mx.w, off));
    }
    if (lane == 0) { redl[wv] = ls; redm[wv] = mx; }
    __syncthreads();
    if (tid == 0) {
        float L = 0.f;
        float4 M = make_float4(-1e30f, -1e30f, -1e30f, -1e30f);
        #pragma unroll
        for (int k = 0; k < 8; ++k) {
            L += redl[k];
            M.x = fmaxf(M.x, redm[k].x);
            M.y = fmaxf(M.y, redm[k].y);
            M.z = fmaxf(M.z, redm[k].z);
            M.w = fmaxf(M.w, redm[k].w);
        }
        atomicAdd(out, L * (1.0f / ((float)NN * (float)NP1)));
        bmax = M;
    }
    __syncthreads();
    const float4 rm = bmax;

    // ---- exp + sum per row (both columns) ----
    const float e0a = __builtin_amdgcn_exp2f((sc0a - rm.x) * L2E);
    const float e1a = __builtin_amdgcn_exp2f((sc1a - rm.y) * L2E);
    const float e2a = __builtin_amdgcn_exp2f((sc2a - rm.z) * L2E);
    const float e3a = __builtin_amdgcn_exp2f((sc3a - rm.w) * L2E);
    const float e0b = __builtin_amdgcn_exp2f((sc0b - rm.x) * L2E);
    const float e1b = __builtin_amdgcn_exp2f((sc1b - rm.y) * L2E);
    const float e2b = __builtin_amdgcn_exp2f((sc2b - rm.z) * L2E);
    const float e3b = __builtin_amdgcn_exp2f((sc3b - rm.w) * L2E);
    float4 e4v = make_float4(0.f, 0.f, 0.f, 0.f);
    if (tid == 0) {
        e4v.x = __builtin_amdgcn_exp2f((sc4sh[0] - rm.x) * L2E);
        e4v.y = __builtin_amdgcn_exp2f((sc4sh[1] - rm.y) * L2E);
        e4v.z = __builtin_amdgcn_exp2f((sc4sh[2] - rm.z) * L2E);
        e4v.w = __builtin_amdgcn_exp2f((sc4sh[3] - rm.w) * L2E);
    }
    float4 es = make_float4(e0a + e0b + e4v.x, e1a + e1b + e4v.y,
                            e2a + e2b + e4v.z, e3a + e3b + e4v.w);
    #pragma unroll
    for (int off = 32; off > 0; off >>= 1) {
        es.x += __shfl_down(es.x, off);
        es.y += __shfl_down(es.y, off);
        es.z += __shfl_down(es.z, off);
        es.w += __shfl_down(es.w, off);
    }
    if (lane == 0) rede[wv] = es;
    __syncthreads();
    if (tid == 0) {
        float4 S = make_float4(0.f, 0.f, 0.f, 0.f);
        #pragma unroll
        for (int k = 0; k < 8; ++k) {
            S.x += rede[k].x; S.y += rede[k].y;
            S.z += rede[k].z; S.w += rede[k].w;
        }
        binv = make_float4(1.f / S.x, 1.f / S.y, 1.f / S.z, 1.f / S.w);
    }
    __syncthreads();
    const float4 iv = binv;

    // ---- write softmax rows (both columns) ----
    float* o0 = out + 1 + (long)(i0 + 0) * NP1;
    float* o1 = out + 1 + (long)(i0 + 1) * NP1;
    float* o2 = out + 1 + (long)(i0 + 2) * NP1;
    float* o3 = out + 1 + (long)(i0 + 3) * NP1;
    o0[tid] = e0a * iv.x;
    o1[tid] = e1a * iv.y;
    o2[tid] = e2a * iv.z;
    o3[tid] = e3a * iv.w;
    o0[jb] = e0b * iv.x;
    o1[jb] = e1b * iv.y;
    o2[jb] = e2b * iv.z;
    o3[jb] = e3b * iv.w;
    if (tid == 0) {
        o0[1024] = e4v.x * iv.x;
        o1[1024] = e4v.y * iv.y;
        o2[1024] = e4v.z * iv.z;
        o3[1024] = e4v.w * iv.w;
    }
    #undef QBODY
    #undef QCOL
    #undef LDXA
    #undef LDXB
}

extern "C" void kernel_launch(void* const* d_in, const int* in_sizes, int n_in,
                              void* d_out, int out_size, void* d_ws, size_t ws_size,
                              hipStream_t stream) {
    const float* sentence = (const float*)d_in[0];
    const int*   target   = (const int*)  d_in[1];
    const float* W1       = (const float*)d_in[2];
    const float* b1       = (const float*)d_in[3];
    const float* W2       = (const float*)d_in[4];
    const float* b2       = (const float*)d_in[5];
    float* out = (float*)d_out;

    float* s1b = (float*)d_ws;                 // 1024*100 floats
    float* E4  = s1b + NN * MID;               // 25*1088*4 floats

    precompute_kernel<<<NN / 2, 256, 0, stream>>>(sentence, W1, b1, s1b, E4, out);
    main_kernel<<<NN / 4, 512, 0, stream>>>(s1b, E4, W2, b2, target, out);
}

// Round 2
// 91.704 us; speedup vs baseline: 1.1050x; 1.1050x over previous
//
#include <hip/hip_runtime.h>

#define H     300
#define MID   100
#define NN    1024
#define NP1   1025
#define JST   1088   // padded j-extent of E4 (E4[25][1088][4] floats)

typedef float v2f __attribute__((ext_vector_type(2)));
static __device__ __forceinline__ v2f sp2(float s) { return (v2f){s, s}; }
static __device__ __forceinline__ v2f fma2(v2f a, v2f b, v2f c) {
    return __builtin_elementwise_fma(a, b, c);
}

// 16-lane-row rotate-add via DPP (VALU pipe, no DS traffic).
template <int CTRL>
static __device__ __forceinline__ float row_ror_add(float v) {
    const int s = __builtin_amdgcn_update_dpp(0, __float_as_int(v), CTRL, 0xF, 0xF, true);
    return v + __int_as_float(s);
}
// lane ^ 16 exchange-add (single DS-pipe swizzle, stays within 32-lane group)
static __device__ __forceinline__ float swz_xor16_add(float v) {
    const int s = __builtin_amdgcn_ds_swizzle(__float_as_int(v), 0x401F);
    return v + __int_as_float(s);
}
// full 32-lane-group sum: 1 ds_swizzle + 4 DPP row_ror adds
static __device__ __forceinline__ float red32(float v) {
    v = swz_xor16_add(v);
    v = row_ror_add<0x128>(v);   // row_ror:8
    v = row_ror_add<0x124>(v);   // row_ror:4
    v = row_ror_add<0x122>(v);   // row_ror:2
    v = row_ror_add<0x121>(v);   // row_ror:1
    return v;
}

// ---------------------------------------------------------------------------
// Kernel A (restructured): 512 blocks x 512 threads; block b -> items iA=2b,
// iB=2b+1. 8 waves; wave -> (half = wv&1, m-range mb = (wv>>1)*25). Each wave
// splits into two 32-lane groups (sub); per step the group computes one
// (m, half) dot for BOTH items. Sentence values preloaded into REGISTERS
// (loop-invariant; no LDS, no __syncthreads). Reduction = 1 ds_swizzle +
// 4 DPP row_ror adds (was 5 shuffle butterflies x2). 13 steps (was 25).
// DS-pipe ops/step: 30 -> 2; occupancy 2 -> 4 waves/SIMD.
// ---------------------------------------------------------------------------
__global__ __launch_bounds__(512) void precompute_kernel(
    const float* __restrict__ sentence,
    const float* __restrict__ W1,
    const float* __restrict__ b1,
    float* __restrict__ s1b,
    float* __restrict__ E4,
    float* __restrict__ out)
{
    const int tid = threadIdx.x;
    const int iA = blockIdx.x * 2, iB = iA + 1;
    const float NL = -1.4426950408889634f;

    if (blockIdx.x == 0) {
        if (tid == 0) out[0] = 0.0f;                              // loss accumulator
        if (tid < MID)
            E4[(long)((tid >> 2) * JST) * 4 + (tid & 3)] = 1.0f;  // j=0 column
    }

    const int lane = tid & 63;
    const int wv   = tid >> 6;        // 0..7
    const int sub  = lane >> 5;       // 0/1: which m within the step
    const int hb   = lane & 31;       // h-lane within the 32-group
    const int half = wv & 1;          // W1 half (s1 vs s2)
    const int mb   = (wv >> 1) * 25;  // m-range base: 0,25,50,75

    // Loop-invariant sentence values -> registers (coalesced 128B group reads)
    const float* sA = sentence + (long)iA * H + hb;
    const float* sB = sentence + (long)iB * H + hb;
    float ra[9], rb[9];
    #pragma unroll
    for (int k = 0; k < 9; ++k) { ra[k] = sA[32 * k]; rb[k] = sB[32 * k]; }
    const bool tl = hb < 12;                       // tail lanes (h = 288+hb < 300)
    const float ra9 = tl ? sA[288] : 0.0f;         // predicated load (OOB-safe)
    const float rb9 = tl ? sB[288] : 0.0f;
    const int h9 = 288 + (tl ? hb : 0);            // clamped tail index (in-bounds)

    for (int q = 0; q < 13; ++q) {
        const int off = 2 * q + sub;
        const int m   = mb + (off < 25 ? off : 24);      // clamp keeps loads in-bounds
        const float* wrow = W1 + (long)m * (2 * H) + half * H;

        float aA, aB;
        {
            const float w0 = wrow[hb];
            aA = w0 * ra[0];
            aB = w0 * rb[0];
        }
        #pragma unroll
        for (int k = 1; k < 9; ++k) {
            const float w = wrow[hb + 32 * k];
            aA = __builtin_fmaf(w, ra[k], aA);
            aB = __builtin_fmaf(w, rb[k], aB);
        }
        {
            const float w9 = wrow[h9];                   // ra9/rb9 zeroed for non-tail lanes
            aA = __builtin_fmaf(w9, ra9, aA);
            aB = __builtin_fmaf(w9, rb9, aB);
        }

        aA = red32(aA);
        aB = red32(aB);

        if (hb == 0 && off < 25) {
            if (half == 0) {
                const float bb = b1[m];
                s1b[iA * MID + m] = aA + bb;
                s1b[iB * MID + m] = aB + bb;
            } else {
                float* base = E4 + (long)((m >> 2) * JST) * 4 + (m & 3);
                base[(long)(iA + 1) * 4] = __builtin_amdgcn_exp2f(aA * NL);
                base[(long)(iB + 1) * 4] = __builtin_amdgcn_exp2f(aB * NL);
            }
        }
    }
}

// ---------------------------------------------------------------------------
// Kernel B: unchanged from round 1 (256 blocks x 512 threads, 4 rows/block,
// 2 columns/thread). Kept identical to isolate kernel A's contribution.
// ---------------------------------------------------------------------------
__global__ __launch_bounds__(512, 2) void main_kernel(
    const float* __restrict__ s1b,
    const float* __restrict__ E4,
    const float* __restrict__ W2,
    const float* __restrict__ b2,
    const int*   __restrict__ target,
    float* __restrict__ out)
{
    __shared__ float4 Fq[MID];          // {F_row0..F_row3}[m]
    __shared__ float4 w4sh[MID / 4];    // W2 m-quads
    __shared__ float  tmp[4][104];      // remainder-column partials per row
    __shared__ float  redl[8];
    __shared__ float4 redm[8];
    __shared__ float4 rede[8];
    __shared__ float  sc4sh[4];
    __shared__ float4 bmax, binv;

    const int i0  = blockIdx.x * 4;
    const int tid = threadIdx.x;
    const int lane = tid & 63, wv = tid >> 6;
    const float NL  = -1.4426950408889634f;
    const float L2E =  1.4426950408889634f;
    const v2f one2 = sp2(1.0f);

    if (tid < MID) {
        Fq[tid] = make_float4(
            __builtin_amdgcn_exp2f(s1b[(i0 + 0) * MID + tid] * NL),
            __builtin_amdgcn_exp2f(s1b[(i0 + 1) * MID + tid] * NL),
            __builtin_amdgcn_exp2f(s1b[(i0 + 2) * MID + tid] * NL),
            __builtin_amdgcn_exp2f(s1b[(i0 + 3) * MID + tid] * NL));
    } else if (tid >= 128 && tid < 128 + MID / 4) {
        const int p = tid - 128;
        w4sh[p] = make_float4(W2[4 * p], W2[4 * p + 1], W2[4 * p + 2], W2[4 * p + 3]);
    }
    const float b2v = b2[0];
    __syncthreads();

    // coalesced: column j reads float4 at E4 + (p*JST + j)*4
    #define LDXA(p_) (*(const float4*)(E4 + ((long)(p_) * JST + tid) * 4))
    #define LDXB(p_) (*(const float4*)(E4 + ((long)(p_) * JST + tid + 512) * 4))

    v2f acc01a = sp2(0.f), acc23a = sp2(0.f);
    v2f acc01b = sp2(0.f), acc23b = sp2(0.f);

    #define QCOL(X, accLo, accHi)                                             \
        do {                                                                  \
            const v2f e0 = sp2((X).x), e1 = sp2((X).y);                       \
            const v2f e2 = sp2((X).z), e3 = sp2((X).w);                       \
            {   /* rows 0,1 */                                                \
                const v2f A = fma2(e0, (v2f){F0.x, F0.y}, one2);              \
                const v2f B = fma2(e1, (v2f){F1.x, F1.y}, one2);              \
                const v2f C = fma2(e2, (v2f){F2.x, F2.y}, one2);              \
                const v2f D = fma2(e3, (v2f){F3.x, F3.y}, one2);              \
                const v2f AB = A * B, CD = C * D, P = AB * CD;                \
                const v2f R = {__builtin_amdgcn_rcpf(P.x),                    \
                               __builtin_amdgcn_rcpf(P.y)};                   \
                const v2f n1 = fma2(w0, B, w1 * A);                           \
                const v2f n2 = fma2(w2v, D, w3 * C);                          \
                accLo = fma2(fma2(n1, CD, n2 * AB), R, accLo);                \
            }                                                                 \
            {   /* rows 2,3 */                                                \
                const v2f A = fma2(e0, (v2f){F0.z, F0.w}, one2);              \
                const v2f B = fma2(e1, (v2f){F1.z, F1.w}, one2);              \
                const v2f C = fma2(e2, (v2f){F2.z, F2.w}, one2);              \
                const v2f D = fma2(e3, (v2f){F3.z, F3.w}, one2);              \
                const v2f AB = A * B, CD = C * D, P = AB * CD;                \
                const v2f R = {__builtin_amdgcn_rcpf(P.x),                    \
                               __builtin_amdgcn_rcpf(P.y)};                   \
                const v2f n1 = fma2(w0, B, w1 * A);                           \
                const v2f n2 = fma2(w2v, D, w3 * C);                          \
                accHi = fma2(fma2(n1, CD, n2 * AB), R, accHi);                \
            }                                                                 \
        } while (0)

    #define QBODY(p_, XA, XB)                                                 \
        do {                                                                  \
            const float4 F0 = Fq[4 * (p_)];                                   \
            const float4 F1 = Fq[4 * (p_) + 1];                               \
            const float4 F2 = Fq[4 * (p_) + 2];                               \
            const float4 F3 = Fq[4 * (p_) + 3];                               \
            const float4 w  = w4sh[p_];                                       \
            const v2f w0 = sp2(w.x), w1 = sp2(w.y);                           \
            const v2f w2v = sp2(w.z), w3 = sp2(w.w);                          \
            QCOL(XA, acc01a, acc23a);                                         \
            QCOL(XB, acc01b, acc23b);                                         \
        } while (0)

    // 25 m-quads, distance-2 software pipeline on the float4 loads
    float4 xa0 = LDXA(0), xb0 = LDXB(0);
    float4 xa1 = LDXA(1), xb1 = LDXB(1);
    #pragma unroll 2
    for (int p = 0; p < 23; ++p) {
        const float4 xan = LDXA(p + 2), xbn = LDXB(p + 2);
        QBODY(p, xa0, xb0);
        xa0 = xa1; xa1 = xan;
        xb0 = xb1; xb1 = xbn;
    }
    QBODY(23, xa0, xb0);
    QBODY(24, xa1, xb1);

    const float sc0a = acc01a.x + b2v, sc1a = acc01a.y + b2v;
    const float sc2a = acc23a.x + b2v, sc3a = acc23a.y + b2v;
    const float sc0b = acc01b.x + b2v, sc1b = acc01b.y + b2v;
    const float sc2b = acc23b.x + b2v, sc3b = acc23b.y + b2v;

    // ---- remainder column j = 1024 (4 rows) ----
    if (tid < MID) {
        const float E = E4[((long)(tid >> 2) * JST + 1024) * 4 + (tid & 3)];
        const float4 F = Fq[tid];
        const float wm = W2[tid];
        tmp[0][tid] = wm * __builtin_amdgcn_rcpf(__builtin_fmaf(E, F.x, 1.f));
        tmp[1][tid] = wm * __builtin_amdgcn_rcpf(__builtin_fmaf(E, F.y, 1.f));
        tmp[2][tid] = wm * __builtin_amdgcn_rcpf(__builtin_fmaf(E, F.z, 1.f));
        tmp[3][tid] = wm * __builtin_amdgcn_rcpf(__builtin_fmaf(E, F.w, 1.f));
    }
    __syncthreads();
    if (wv < 4) {
        float v = tmp[wv][lane] + ((lane < MID - 64) ? tmp[wv][lane + 64] : 0.f);
        #pragma unroll
        for (int off = 32; off > 0; off >>= 1) v += __shfl_down(v, off);
        if (lane == 0) sc4sh[wv] = v + b2v;
    }
    __syncthreads();

    // ---- loss + row-max (both columns folded per thread) ----
    const int tg0 = target[i0], tg1 = target[i0 + 1];
    const int tg2 = target[i0 + 2], tg3 = target[i0 + 3];
    const int jb = tid + 512;
    float ls = fabsf(sc0a - ((tid == tg0) ? 1.f : 0.f))
             + fabsf(sc1a - ((tid == tg1) ? 1.f : 0.f))
             + fabsf(sc2a - ((tid == tg2) ? 1.f : 0.f))
             + fabsf(sc3a - ((tid == tg3) ? 1.f : 0.f))
             + fabsf(sc0b - ((jb == tg0) ? 1.f : 0.f))
             + fabsf(sc1b - ((jb == tg1) ? 1.f : 0.f))
             + fabsf(sc2b - ((jb == tg2) ? 1.f : 0.f))
             + fabsf(sc3b - ((jb == tg3) ? 1.f : 0.f));
    float4 mx = make_float4(fmaxf(sc0a, sc0b), fmaxf(sc1a, sc1b),
                            fmaxf(sc2a, sc2b), fmaxf(sc3a, sc3b));
    if (tid == 0) {
        ls += fabsf(sc4sh[0] - ((1024 == tg0) ? 1.f : 0.f))
            + fabsf(sc4sh[1] - ((1024 == tg1) ? 1.f : 0.f))
            + fabsf(sc4sh[2] - ((1024 == tg2) ? 1.f : 0.f))
            + fabsf(sc4sh[3] - ((1024 == tg3) ? 1.f : 0.f));
        mx.x = fmaxf(mx.x, sc4sh[0]);
        mx.y = fmaxf(mx.y, sc4sh[1]);
        mx.z = fmaxf(mx.z, sc4sh[2]);
        mx.w = fmaxf(mx.w, sc4sh[3]);
    }
    #pragma unroll
    for (int off = 32; off > 0; off >>= 1) {
        ls += __shfl_down(ls, off);
        mx.x = fmaxf(mx.x, __shfl_down(mx.x, off));
        mx.y = fmaxf(mx.y, __shfl_down(mx.y, off));
        mx.z = fmaxf(mx.z, __shfl_down(mx.z, off));
        mx.w = fmaxf(mx.w, __shfl_down(mx.w, off));
    }
    if (lane == 0) { redl[wv] = ls; redm[wv] = mx; }
    __syncthreads();
    if (tid == 0) {
        float L = 0.f;
        float4 M = make_float4(-1e30f, -1e30f, -1e30f, -1e30f);
        #pragma unroll
        for (int k = 0; k < 8; ++k) {
            L += redl[k];
            M.x = fmaxf(M.x, redm[k].x);
            M.y = fmaxf(M.y, redm[k].y);
            M.z = fmaxf(M.z, redm[k].z);
            M.w = fmaxf(M.w, redm[k].w);
        }
        atomicAdd(out, L * (1.0f / ((float)NN * (float)NP1)));
        bmax = M;
    }
    __syncthreads();
    const float4 rm = bmax;

    // ---- exp + sum per row (both columns) ----
    const float e0a = __builtin_amdgcn_exp2f((sc0a - rm.x) * L2E);
    const float e1a = __builtin_amdgcn_exp2f((sc1a - rm.y) * L2E);
    const float e2a = __builtin_amdgcn_exp2f((sc2a - rm.z) * L2E);
    const float e3a = __builtin_amdgcn_exp2f((sc3a - rm.w) * L2E);
    const float e0b = __builtin_amdgcn_exp2f((sc0b - rm.x) * L2E);
    const float e1b = __builtin_amdgcn_exp2f((sc1b - rm.y) * L2E);
    const float e2b = __builtin_amdgcn_exp2f((sc2b - rm.z) * L2E);
    const float e3b = __builtin_amdgcn_exp2f((sc3b - rm.w) * L2E);
    float4 e4v = make_float4(0.f, 0.f, 0.f, 0.f);
    if (tid == 0) {
        e4v.x = __builtin_amdgcn_exp2f((sc4sh[0] - rm.x) * L2E);
        e4v.y = __builtin_amdgcn_exp2f((sc4sh[1] - rm.y) * L2E);
        e4v.z = __builtin_amdgcn_exp2f((sc4sh[2] - rm.z) * L2E);
        e4v.w = __builtin_amdgcn_exp2f((sc4sh[3] - rm.w) * L2E);
    }
    float4 es = make_float4(e0a + e0b + e4v.x, e1a + e1b + e4v.y,
                            e2a + e2b + e4v.z, e3a + e3b + e4v.w);
    #pragma unroll
    for (int off = 32; off > 0; off >>= 1) {
        es.x += __shfl_down(es.x, off);
        es.y += __shfl_down(es.y, off);
        es.z += __shfl_down(es.z, off);
        es.w += __shfl_down(es.w, off);
    }
    if (lane == 0) rede[wv] = es;
    __syncthreads();
    if (tid == 0) {
        float4 S = make_float4(0.f, 0.f, 0.f, 0.f);
        #pragma unroll
        for (int k = 0; k < 8; ++k) {
            S.x += rede[k].x; S.y += rede[k].y;
            S.z += rede[k].z; S.w += rede[k].w;
        }
        binv = make_float4(1.f / S.x, 1.f / S.y, 1.f / S.z, 1.f / S.w);
    }
    __syncthreads();
    const float4 iv = binv;

    // ---- write softmax rows (both columns) ----
    float* o0 = out + 1 + (long)(i0 + 0) * NP1;
    float* o1 = out + 1 + (long)(i0 + 1) * NP1;
    float* o2 = out + 1 + (long)(i0 + 2) * NP1;
    float* o3 = out + 1 + (long)(i0 + 3) * NP1;
    o0[tid] = e0a * iv.x;
    o1[tid] = e1a * iv.y;
    o2[tid] = e2a * iv.z;
    o3[tid] = e3a * iv.w;
    o0[jb] = e0b * iv.x;
    o1[jb] = e1b * iv.y;
    o2[jb] = e2b * iv.z;
    o3[jb] = e3b * iv.w;
    if (tid == 0) {
        o0[1024] = e4v.x * iv.x;
        o1[1024] = e4v.y * iv.y;
        o2[1024] = e4v.z * iv.z;
        o3[1024] = e4v.w * iv.w;
    }
    #undef QBODY
    #undef QCOL
    #undef LDXA
    #undef LDXB
}

extern "C" void kernel_launch(void* const* d_in, const int* in_sizes, int n_in,
                              void* d_out, int out_size, void* d_ws, size_t ws_size,
                              hipStream_t stream) {
    const float* sentence = (const float*)d_in[0];
    const int*   target   = (const int*)  d_in[1];
    const float* W1       = (const float*)d_in[2];
    const float* b1       = (const float*)d_in[3];
    const float* W2       = (const float*)d_in[4];
    const float* b2       = (const float*)d_in[5];
    float* out = (float*)d_out;

    float* s1b = (float*)d_ws;                 // 1024*100 floats
    float* E4  = s1b + NN * MID;               // 25*1088*4 floats

    precompute_kernel<<<NN / 2, 512, 0, stream>>>(sentence, W1, b1, s1b, E4, out);
    main_kernel<<<NN / 4, 512, 0, stream>>>(s1b, E4, W2, b2, target, out);
}